// Round 1
// baseline (704.448 us; speedup 1.0000x reference)
//
#include <hip/hip_runtime.h>

#define B_ 4096
#define L_ 200
#define D_ 128

__global__ __launch_bounds__(256, 8) void tahe_kernel(
    const float* __restrict__ rec,     // [B,L,D] recentTimeRepresentations
    const float* __restrict__ cur,     // [B,D]   curTimeRepresentation
    const int*   __restrict__ ts,      // [B,L]   recentTimestamps
    const float* __restrict__ item,    // [B,L,D] recentItemEmbeddings
    float*       __restrict__ out)     // [B,D]   userHistoryRepresentation
{
    const int b    = blockIdx.x;
    const int tid  = threadIdx.x;
    const int wave = tid >> 6;          // 0..3
    const int grp  = tid >> 5;          // 0..7  (32-lane half-wave group)
    const int half = (tid >> 5) & 1;    // 0/1 within wave
    const int sub  = tid & 31;          // lane within 32-group

    __shared__ int    s_active[L_];
    __shared__ int    s_n;
    __shared__ float4 s_red[4][32];

    if (tid == 0) s_n = 0;
    __syncthreads();

    // Compact the active (mask==1) l-indices. ~50% of rows are masked out;
    // skipping them halves HBM traffic (each row is 512B of whole cache lines).
    if (tid < L_) {
        if (ts[b * L_ + tid] > 0) {
            int p = atomicAdd(&s_n, 1);
            s_active[p] = tid;
        }
    }

    // Normalize cur: each lane holds cur_n[sub*4 .. sub*4+3] (both halves identical).
    const float4 c4 = *(const float4*)(cur + b * D_ + sub * 4);
    float css = c4.x*c4.x + c4.y*c4.y + c4.z*c4.z + c4.w*c4.w;
    #pragma unroll
    for (int m = 1; m <= 16; m <<= 1) css += __shfl_xor(css, m);
    float crs = rsqrtf(fmaxf(css, 1e-12f));
    crs = crs * (1.5f - 0.5f * css * crs * crs);   // one NR step for accuracy
    float4 cn;
    cn.x = c4.x * crs; cn.y = c4.y * crs; cn.z = c4.z * crs; cn.w = c4.w * crs;

    __syncthreads();
    const int n = s_n;

    const float* recb  = rec  + (size_t)b * (L_ * D_);
    const float* itemb = item + (size_t)b * (L_ * D_);

    float4 acc = make_float4(0.f, 0.f, 0.f, 0.f);

    // Each 32-lane group handles one active row per iteration: 16B/lane float4
    // loads (fully coalesced 512B/row), 5-step shuffle reduction, fused rsqrt.
    for (int i = grp; i < n; i += 8) {
        const int l = s_active[i];
        const float4 r4 = *(const float4*)(recb  + l * D_ + sub * 4);
        const float4 t4 = *(const float4*)(itemb + l * D_ + sub * 4);

        float pd = cn.x*r4.x + cn.y*r4.y + cn.z*r4.z + cn.w*r4.w;
        float ps = r4.x*r4.x + r4.y*r4.y + r4.z*r4.z + r4.w*r4.w;
        #pragma unroll
        for (int m = 1; m <= 16; m <<= 1) {
            pd += __shfl_xor(pd, m);
            ps += __shfl_xor(ps, m);
        }
        float rs = rsqrtf(fmaxf(ps, 1e-12f));
        rs = rs * (1.5f - 0.5f * ps * rs * rs);    // NR refinement
        const float w = fmaf(pd * rs, 0.5f, 0.5f); // (cos + 1) * 0.5, mask==1 here

        acc.x = fmaf(w, t4.x, acc.x);
        acc.y = fmaf(w, t4.y, acc.y);
        acc.z = fmaf(w, t4.z, acc.z);
        acc.w = fmaf(w, t4.w, acc.w);
    }

    // Combine the two halves of each wave (same d-range) via xor-32 shuffle.
    acc.x += __shfl_xor(acc.x, 32);
    acc.y += __shfl_xor(acc.y, 32);
    acc.z += __shfl_xor(acc.z, 32);
    acc.w += __shfl_xor(acc.w, 32);

    if (half == 0) s_red[wave][sub] = acc;
    __syncthreads();

    // Cross-wave combine + coalesced 512B store.
    if (tid < D_) {
        const float* rf = (const float*)s_red;
        float v = rf[tid] + rf[D_ + tid] + rf[2 * D_ + tid] + rf[3 * D_ + tid];
        out[b * D_ + tid] = v;
    }
}

extern "C" void kernel_launch(void* const* d_in, const int* in_sizes, int n_in,
                              void* d_out, int out_size, void* d_ws, size_t ws_size,
                              hipStream_t stream) {
    const float* rec  = (const float*)d_in[0];
    const float* cur  = (const float*)d_in[1];
    const int*   ts   = (const int*)d_in[2];
    const float* item = (const float*)d_in[3];
    float*       out  = (float*)d_out;
    tahe_kernel<<<B_, 256, 0, stream>>>(rec, cur, ts, item, out);
}

// Round 2
// 701.452 us; speedup vs baseline: 1.0043x; 1.0043x over previous
//
#include <hip/hip_runtime.h>

#define B_ 4096
#define L_ 200
#define D_ 128

__global__ __launch_bounds__(256, 8) void tahe_kernel(
    const float* __restrict__ rec,     // [B,L,D] recentTimeRepresentations
    const float* __restrict__ cur,     // [B,D]   curTimeRepresentation
    const int*   __restrict__ ts,      // [B,L]   recentTimestamps
    const float* __restrict__ item,    // [B,L,D] recentItemEmbeddings
    float*       __restrict__ out)     // [B,D]   userHistoryRepresentation
{
    const int b   = blockIdx.x;
    const int tid = threadIdx.x;

    __shared__ int    s_act[L_];   // compacted active l indices
    __shared__ float  s_w[L_];     // weight per compacted index
    __shared__ int    s_n;
    __shared__ float  s_cinv;      // 1/||cur||
    __shared__ float4 s_red[8][32];

    if (tid == 0) s_n = 0;
    __syncthreads();

    // Compact active (mask==1) indices; ~50% masked -> skip those rows' 1KB
    // of HBM traffic entirely. Order nondeterminism only reorders an fp sum.
    if (tid < L_) {
        if (ts[b * L_ + tid] > 0) {
            int p = atomicAdd(&s_n, 1);
            s_act[p] = tid;
        }
    }

    // Wave 0, lanes 0..31: ||cur||^-1 (the only wide shuffle reduction, once).
    if (tid < 32) {
        const float4 c4 = *(const float4*)(cur + b * D_ + tid * 4);
        float ss = c4.x*c4.x + c4.y*c4.y + c4.z*c4.z + c4.w*c4.w;
        #pragma unroll
        for (int m = 1; m <= 16; m <<= 1) ss += __shfl_xor(ss, m);
        if (tid == 0) {
            float r = rsqrtf(fmaxf(ss, 1e-12f));
            r = r * (1.5f - 0.5f * ss * r * r);   // NR step for fp32 accuracy
            s_cinv = r;
        }
    }
    __syncthreads();

    const int   n    = s_n;
    const float cinv = s_cinv;
    const float* recb  = rec  + (size_t)b * (L_ * D_);
    const float* itemb = item + (size_t)b * (L_ * D_);

    // ---- Phase A: similarities. 8-lane group per row, 32 groups.
    // 4 independent float4 loads/lane (MLP), only 3 shuffle levels per row.
    {
        const int g8 = tid >> 3;   // 0..31
        const int j  = tid & 7;    // lane within group; covers chunks j+8k
        float4 c[4];
        #pragma unroll
        for (int k = 0; k < 4; ++k)
            c[k] = *(const float4*)(cur + b * D_ + (j + 8 * k) * 4);

        for (int i = g8; i < n; i += 32) {
            const int l = s_act[i];
            const float* r = recb + (size_t)l * D_;
            float pd = 0.f, ps = 0.f;
            #pragma unroll
            for (int k = 0; k < 4; ++k) {
                const float4 r4 = *(const float4*)(r + (j + 8 * k) * 4);
                pd = fmaf(c[k].x, r4.x, fmaf(c[k].y, r4.y, fmaf(c[k].z, r4.z, fmaf(c[k].w, r4.w, pd))));
                ps = fmaf(r4.x, r4.x, fmaf(r4.y, r4.y, fmaf(r4.z, r4.z, fmaf(r4.w, r4.w, ps))));
            }
            #pragma unroll
            for (int m = 1; m <= 4; m <<= 1) {
                pd += __shfl_xor(pd, m);
                ps += __shfl_xor(ps, m);
            }
            if (j == 0) {
                float rs = rsqrtf(fmaxf(ps, 1e-12f));
                rs = rs * (1.5f - 0.5f * ps * rs * rs);
                s_w[i] = fmaf(pd * rs * cinv, 0.5f, 0.5f);  // mask==1 here
            }
        }
    }
    __syncthreads();

    // ---- Phase B: weighted pooling. 32-lane group per row, 8 groups.
    // Per iteration: one coalesced 512B load + LDS broadcast + 4 fma.
    // No cross-lane ops -> compiler keeps many loads in flight.
    const int g   = tid >> 5;   // 0..7
    const int sub = tid & 31;   // float4 chunk owned by this lane
    float4 acc = make_float4(0.f, 0.f, 0.f, 0.f);

    for (int i = g; i < n; i += 8) {
        const int   l = s_act[i];
        const float w = s_w[i];
        const float4 t4 = *(const float4*)(itemb + (size_t)l * D_ + sub * 4);
        acc.x = fmaf(w, t4.x, acc.x);
        acc.y = fmaf(w, t4.y, acc.y);
        acc.z = fmaf(w, t4.z, acc.z);
        acc.w = fmaf(w, t4.w, acc.w);
    }

    s_red[g][sub] = acc;
    __syncthreads();

    // Cross-group combine + coalesced 512B store (conflict-free LDS reads).
    if (tid < D_) {
        const int chunk = tid >> 2, comp = tid & 3;
        float v = 0.f;
        #pragma unroll
        for (int gg = 0; gg < 8; ++gg) {
            const float* rf = (const float*)&s_red[gg][chunk];
            v += rf[comp];
        }
        out[b * D_ + tid] = v;
    }
}

extern "C" void kernel_launch(void* const* d_in, const int* in_sizes, int n_in,
                              void* d_out, int out_size, void* d_ws, size_t ws_size,
                              hipStream_t stream) {
    const float* rec  = (const float*)d_in[0];
    const float* cur  = (const float*)d_in[1];
    const int*   ts   = (const int*)d_in[2];
    const float* item = (const float*)d_in[3];
    float*       out  = (float*)d_out;
    tahe_kernel<<<B_, 256, 0, stream>>>(rec, cur, ts, item, out);
}